// Round 2
// baseline (168.125 us; speedup 1.0000x reference)
//
#include <hip/hip_runtime.h>
#include <hip/hip_bf16.h>
#include <stdint.h>

// Problem constants: N=8, D1=1024, D2=1024, B=1024, D = D1*D2 = 2^20
#define DD (1 << 20)

typedef float v4f __attribute__((ext_vector_type(4)));
typedef __bf16 bf16x8 __attribute__((ext_vector_type(8)));

struct Scalars {
  float s;             // step size at this stage
  int   uniform;       // 1 if all rows in one group
  float coef[8];       // gradg[gid[i]] per sorted position i
  float cnti[8];       // max(counts[gid[i]],1) per sorted position i
  int   isend[8];      // 1 if sorted position i ends its group
};

struct Partial {       // per-block gap stats (1024 blocks now)
  double g[7];
  double mx;
};

static __device__ __forceinline__ unsigned short f2bf(float v) {
  unsigned u = __float_as_uint(v);
  u += 0x7fffu + ((u >> 16) & 1u);   // round-to-nearest-even
  return (unsigned short)(u >> 16);
}

// keyed 19-CE Batcher network; lexicographic (val, idx) == stable argsort
#define CE2(a, b)                                                        \
  { float ra = r[a], rb = r[b]; int oa = ord[a], ob = ord[b];            \
    bool sw = (ra > rb) || (ra == rb && oa > ob);                        \
    r[a] = sw ? rb : ra; r[b] = sw ? ra : rb;                            \
    ord[a] = sw ? ob : oa; ord[b] = sw ? oa : ob; }

#define SORTNET8                                                          \
  CE2(0,1) CE2(2,3) CE2(4,5) CE2(6,7)                                     \
  CE2(0,2) CE2(1,3) CE2(4,6) CE2(5,7)                                     \
  CE2(1,2) CE2(5,6)                                                       \
  CE2(0,4) CE2(1,5) CE2(2,6) CE2(3,7)                                     \
  CE2(2,4) CE2(3,5)                                                       \
  CE2(1,2) CE2(3,4) CE2(5,6)

// value-only network (stats / uniform path need only sorted values)
#define CEV(a, b) { float ra = q[a], rb = q[b]; q[a] = fminf(ra, rb); q[b] = fmaxf(ra, rb); }
#define SORTNET8V                                                         \
  CEV(0,1) CEV(2,3) CEV(4,5) CEV(6,7)                                     \
  CEV(0,2) CEV(1,3) CEV(4,6) CEV(5,7)                                     \
  CEV(1,2) CEV(5,6)                                                       \
  CEV(0,4) CEV(1,5) CEV(2,6) CEV(3,7)                                     \
  CEV(2,4) CEV(3,5)                                                       \
  CEV(1,2) CEV(3,4) CEV(5,6)

// block-reduce 7 gap sums + max, write to po
static __device__ __forceinline__ void stats_block_reduce(float dl[7], float mx,
                                                          Partial* __restrict__ po) {
#pragma unroll
  for (int off = 32; off; off >>= 1) {
#pragma unroll
    for (int g = 0; g < 7; ++g) dl[g] += __shfl_down(dl[g], off, 64);
    mx = fmaxf(mx, __shfl_down(mx, off, 64));
  }
  __shared__ double wsum[4][7];
  __shared__ float wmax[4];
  int lane = threadIdx.x & 63, wv = threadIdx.x >> 6;
  if (lane == 0) {
#pragma unroll
    for (int g = 0; g < 7; ++g) wsum[wv][g] = (double)dl[g];
    wmax[wv] = mx;
  }
  __syncthreads();
  if (threadIdx.x == 0) {
#pragma unroll
    for (int g = 0; g < 7; ++g)
      po->g[g] = wsum[0][g] + wsum[1][g] + wsum[2][g] + wsum[3][g];
    po->mx = (double)fmaxf(fmaxf(wmax[0], wmax[1]), fmaxf(wmax[2], wmax[3]));
  }
}

// every block redundantly reduces mmpart[1024] -> s0 (8 KB from L2, ~free)
static __device__ __forceinline__ float compute_s0(const float2* __restrict__ mmpart) {
  __shared__ float2 wmm[4];
  __shared__ float sS0;
  int t = threadIdx.x;
  float mn = 3.4e38f, mxv = -3.4e38f;
#pragma unroll
  for (int j = 0; j < 4; ++j) {
    float2 p = mmpart[j * 256 + t];
    mn = fminf(mn, p.x); mxv = fmaxf(mxv, p.y);
  }
#pragma unroll
  for (int off = 32; off; off >>= 1) {
    mn = fminf(mn, __shfl_down(mn, off, 64));
    mxv = fmaxf(mxv, __shfl_down(mxv, off, 64));
  }
  int lane = t & 63, wv = t >> 6;
  if (lane == 0) wmm[wv] = make_float2(mn, mxv);
  __syncthreads();
  if (t == 0) {
    for (int i = 1; i < 4; ++i) { mn = fminf(mn, wmm[i].x); mxv = fmaxf(mxv, wmm[i].y); }
    sS0 = (mxv - mn) / 3.0f;        // RES_DENOS[0] = 3.0
  }
  __syncthreads();
  return sS0;
}

// every block redundantly reduces part[1024] (64 KB from L2); result valid on t==0 only
static __device__ __forceinline__ void reduce_partials(const Partial* __restrict__ part,
                                                       double g[7], double& mx) {
  __shared__ double sg[4][8];
  int t = threadIdx.x;
  __syncthreads();               // protect sg reuse across calls
#pragma unroll
  for (int i = 0; i < 7; ++i) g[i] = 0.0;
  mx = 0.0;
#pragma unroll
  for (int j = 0; j < 4; ++j) {
    const Partial& p = part[j * 256 + t];
#pragma unroll
    for (int i = 0; i < 7; ++i) g[i] += p.g[i];
    mx = fmax(mx, p.mx);
  }
#pragma unroll
  for (int off = 32; off; off >>= 1) {
#pragma unroll
    for (int i = 0; i < 7; ++i) g[i] += __shfl_down(g[i], off, 64);
    mx = fmax(mx, __shfl_down(mx, off, 64));
  }
  int lane = t & 63, wv = t >> 6;
  if (lane == 0) {
#pragma unroll
    for (int i = 0; i < 7; ++i) sg[wv][i] = g[i];
    sg[wv][7] = mx;
  }
  __syncthreads();
  if (t == 0) {
#pragma unroll
    for (int i = 0; i < 7; ++i) g[i] = sg[0][i] + sg[1][i] + sg[2][i] + sg[3][i];
    mx = fmax(fmax(sg[0][7], sg[1][7]), fmax(sg[2][7], sg[3][7]));
  }
}

// exact mirror of the former k_scalars2 t==0 tail (call on t==0 only; sc in LDS)
static __device__ void make_scalars(const double g[7], double mx, float s_prev, float deno,
                                    float thres0, Scalars* sc, bool* sat) {
  float s = s_prev / deno;
  sc->s = s;
  float md = (float)mx;
  float sigT = 1.f / (1.f + expf(-thres0));
  float sp[7], bb[7];
  float zmax = -1e30f;
  for (int gg = 0; gg < 7; ++gg) {
    float mean = (float)(g[gg] / ((double)DD * (double)md));
    float z = (mean - sigT) / 0.01f;     // SPLIT_TEMP
    zmax = fmaxf(zmax, z);
    sp[gg] = 1.f / (1.f + expf(-z));
    bb[gg] = rintf(sp[gg]);              // jnp.round = RNE
  }
  int gid[8]; gid[0] = 0;
  for (int i = 1; i < 8; ++i) gid[i] = gid[i - 1] + (int)bb[i - 1];
  float counts[8] = {0, 0, 0, 0, 0, 0, 0, 0};
  for (int i = 0; i < 8; ++i) counts[gid[i]] += 1.f;
  float lsum[8] = {0, 0, 0, 0, 0, 0, 0, 0};
  for (int i = 0; i < 7; ++i) {
    float f = (bb[i] == 1.f) ? sp[i] : (1.f - sp[i]);
    lsum[gid[i]] += logf(f);
  }
  float gradg[8];
  for (int gg = 0; gg < 8; ++gg) gradg[gg] = expf(lsum[gg]);
  for (int i = 0; i < 8; ++i) {
    sc->coef[i] = gradg[gid[i]];
    sc->cnti[i] = fmaxf(counts[gid[i]], 1.f);
    sc->isend[i] = (i == 7) || (gid[i + 1] != gid[i]);
  }
  int uni = (gid[7] == 0) ? 1 : 0;
  sc->uniform = uni;
  // saturation certain -> next stage is analytic (b=0, coef=1, cnti=8), bit-exact
  *sat = (uni && zmax < -21.0f);
}

// ---------------- general per-column update core (keyed sort + scatter) ----------------
static __device__ __forceinline__ void update_core(const float u[8], const float vo[8],
                                                   const Scalars* __restrict__ sc,
                                                   float vnew[8]) {
  float s = sc->s;
  float coef[8], cnti[8]; int isend[8];
#pragma unroll
  for (int i = 0; i < 8; ++i) { coef[i] = sc->coef[i]; cnti[i] = sc->cnti[i]; isend[i] = sc->isend[i]; }
  float r[8]; int ord[8];
#pragma unroll
  for (int n = 0; n < 8; ++n) { r[n] = u[n] - vo[n]; ord[n] = n; }
  SORTNET8
  float endsum[8]; float a = 0.f;
#pragma unroll
  for (int i = 0; i < 8; ++i) { a += r[i]; endsum[i] = a; if (isend[i]) a = 0.f; }
  float t[8]; float gsv = 0.f;
#pragma unroll
  for (int i = 7; i >= 0; --i) {
    if (isend[i]) gsv = endsum[i];
    t[i] = coef[i] * (gsv / cnti[i]);
  }
#pragma unroll
  for (int n = 0; n < 8; ++n) {
    float tv = 0.f;
#pragma unroll
    for (int i = 0; i < 8; ++i) tv = (ord[i] == n) ? t[i] : tv;
    vnew[n] = vo[n] + s * floorf(tv / s);
  }
}

// uniform (single-group) core: value-sort for the bit-exact sorted-order sum
static __device__ __forceinline__ float uniform_delta(const float u[8], const float vo[8],
                                                      float coef0, float cnt0, float s) {
  float q[8];
#pragma unroll
  for (int n = 0; n < 8; ++n) q[n] = u[n] - vo[n];
  SORTNET8V
  float a = 0.f;
#pragma unroll
  for (int i = 0; i < 8; ++i) a += q[i];
  float t = coef0 * (a / cnt0);
  return s * floorf(t / s);
}

static __device__ __forceinline__ void apply_update(const float u[8], const float vo[8],
                                                    const Scalars* __restrict__ sc,
                                                    float vnew[8]) {
  if (sc->uniform) {
    float c = uniform_delta(u, vo, sc->coef[0], sc->cnti[0], sc->s);
#pragma unroll
    for (int n = 0; n < 8; ++n) vnew[n] = vo[n] + c;
  } else {
    update_core(u, vo, sc, vnew);
  }
}

// ---------------- k1: minmax partials (1024 blocks) + x -> bf16 xT pack (2048 blocks) --
__global__ __launch_bounds__(256)
void k1_minmax_xpack(const float4* __restrict__ U4, float2* __restrict__ mmpart,
                     const float* __restrict__ x, unsigned short* __restrict__ xT) {
  int tid = threadIdx.x;
  if (blockIdx.x < 1024) {
    int bid = blockIdx.x;
    float mn = 3.4e38f, mx = -3.4e38f;
#pragma unroll
    for (int j = 0; j < 8; ++j) {
      float4 v = U4[(size_t)(bid * 8 + j) * 256 + tid];
      mn = fminf(mn, fminf(fminf(v.x, v.y), fminf(v.z, v.w)));
      mx = fmaxf(mx, fmaxf(fmaxf(v.x, v.y), fmaxf(v.z, v.w)));
    }
#pragma unroll
    for (int off = 32; off; off >>= 1) {
      mn = fminf(mn, __shfl_down(mn, off, 64));
      mx = fmaxf(mx, __shfl_down(mx, off, 64));
    }
    __shared__ float2 w4[4];
    if ((tid & 63) == 0) w4[tid >> 6] = make_float2(mn, mx);
    __syncthreads();
    if (tid == 0) {
      for (int i = 1; i < 4; ++i) { mn = fminf(mn, w4[i].x); mx = fmaxf(mx, w4[i].y); }
      mmpart[bid] = make_float2(mn, mx);
    }
  } else {
    int bid2 = blockIdx.x - 1024;          // 0..2047
#pragma unroll
    for (int j = 0; j < 4; ++j) {
      int i = j * (2048 * 256) + bid2 * 256 + tid;
      int kq = i & 255;
      int b  = (i >> 8) & 1023;
      int n  = i >> 18;
      float4 v = *(const float4*)(x + ((size_t)(b * 8 + n) << 10) + (kq << 2));
      ushort4 o = make_ushort4(f2bf(v.x), f2bf(v.y), f2bf(v.z), f2bf(v.w));
      *(ushort4*)(xT + (((size_t)(n << 10 | b)) << 10) + (kq << 2)) = o;
    }
  }
}

// ---------------- k2: s0 inline + stage-1 gap stats (1024 blocks, 4 cols/thread) ------
__global__ __launch_bounds__(256)
void k2_stats0(const float* __restrict__ U, const float2* __restrict__ mmpart,
               Partial* __restrict__ part) {
  float s0 = compute_s0(mmpart);
  int t = threadIdx.x;
  size_t d0 = (size_t)blockIdx.x * 1024 + t * 4;
  float4 u4[8];
#pragma unroll
  for (int n = 0; n < 8; ++n) u4[n] = *(const float4*)(U + ((size_t)n << 20) + d0);
  float dl[7] = {0, 0, 0, 0, 0, 0, 0};
  float mxv = 0.f;
#pragma unroll
  for (int j = 0; j < 4; ++j) {
    float q[8];
#pragma unroll
    for (int n = 0; n < 8; ++n) {
      float u = ((const float*)&u4[n])[j];
      q[n] = u - s0 * floorf(u / s0);
    }
    SORTNET8V
#pragma unroll
    for (int g = 0; g < 7; ++g) { float dd = q[g + 1] - q[g]; dl[g] += dd; mxv = fmaxf(mxv, dd); }
  }
  stats_block_reduce(dl, mxv, &part[blockIdx.x]);
}

// ---------------- k3a: sc1 inline; early-out if stage-2 analytic; else stage-2 stats ---
__global__ __launch_bounds__(256)
void k3a_stats1(const float* __restrict__ U, const float2* __restrict__ mmpart,
                const Partial* __restrict__ part, Partial* __restrict__ part2,
                const float* __restrict__ thres) {
  __shared__ Scalars ssc1;
  __shared__ int ssat;
  float s0 = compute_s0(mmpart);
  double g[7]; double mx;
  reduce_partials(part, g, mx);
  if (threadIdx.x == 0) {
    bool sat;
    make_scalars(g, mx, s0, 5.0f, thres[0], &ssc1, &sat);
    ssat = sat ? 1 : 0;
  }
  __syncthreads();
  if (ssat) return;                        // stage 2 analytic: no stats pass needed

  int t = threadIdx.x;
  size_t d0 = (size_t)blockIdx.x * 1024 + t * 4;
  float4 u4[8];
#pragma unroll
  for (int n = 0; n < 8; ++n) u4[n] = *(const float4*)(U + ((size_t)n << 20) + d0);
  float dl[7] = {0, 0, 0, 0, 0, 0, 0};
  float mxv = 0.f;
#pragma unroll
  for (int j = 0; j < 4; ++j) {
    float u[8], v0[8], v1[8];
#pragma unroll
    for (int n = 0; n < 8; ++n) {
      u[n] = ((const float*)&u4[n])[j];
      v0[n] = s0 * floorf(u[n] / s0);
    }
    apply_update(u, v0, &ssc1, v1);
    float q[8];
#pragma unroll
    for (int n = 0; n < 8; ++n) q[n] = u[n] - v1[n];
    SORTNET8V
#pragma unroll
    for (int gg = 0; gg < 7; ++gg) { float dd = q[gg + 1] - q[gg]; dl[gg] += dd; mxv = fmaxf(mxv, dd); }
  }
  stats_block_reduce(dl, mxv, &part2[blockIdx.x]);
}

// ---------------- k3b: sc1+sc2 inline -> v0 -> v1 -> v2 -> bf16 -> wT[n][l][k] ---------
__global__ __launch_bounds__(256)
void k3b_final(const float* __restrict__ U, const float2* __restrict__ mmpart,
               const Partial* __restrict__ part, const Partial* __restrict__ part2,
               const float* __restrict__ thres, unsigned short* __restrict__ wT) {
  __shared__ Scalars ssc1, ssc2;
  __shared__ int ssat;
  __shared__ unsigned short stile[8][32][34];
  int t = threadIdx.x;
  float s0 = compute_s0(mmpart);
  {
    double g[7]; double mx;
    reduce_partials(part, g, mx);
    if (t == 0) {
      bool sat;
      make_scalars(g, mx, s0, 5.0f, thres[0], &ssc1, &sat);
      ssat = sat ? 1 : 0;
    }
  }
  __syncthreads();
  if (!ssat) {
    double g[7]; double mx;
    reduce_partials(part2, g, mx);
    if (t == 0) {
      bool sat2;
      make_scalars(g, mx, ssc1.s, 17.0f, thres[0], &ssc2, &sat2);
    }
  } else if (t == 0) {
    ssc2.s = ssc1.s / 17.0f;
    ssc2.uniform = 1;
#pragma unroll
    for (int i = 0; i < 8; ++i) {
      ssc2.coef[i] = 1.0f;
      ssc2.cnti[i] = 8.0f;
      ssc2.isend[i] = (i == 7) ? 1 : 0;
    }
  }
  __syncthreads();

  int k0 = (blockIdx.x >> 5) * 32;
  int l0 = (blockIdx.x & 31) * 32;
  int kk = t >> 3;            // 0..31
  int lq = t & 7;             // 4 cols each
  int d0 = (k0 + kk) * 1024 + l0 + lq * 4;
  float4 u4[8];
#pragma unroll
  for (int n = 0; n < 8; ++n) u4[n] = *(const float4*)(U + ((size_t)n << 20) + d0);
#pragma unroll
  for (int j = 0; j < 4; ++j) {
    float u[8], v0[8], v1[8], v2[8];
#pragma unroll
    for (int n = 0; n < 8; ++n) {
      u[n] = ((const float*)&u4[n])[j];
      v0[n] = s0 * floorf(u[n] / s0);
    }
    apply_update(u, v0, &ssc1, v1);
    apply_update(u, v1, &ssc2, v2);
#pragma unroll
    for (int n = 0; n < 8; ++n) stile[n][kk][lq * 4 + j] = f2bf(v2[n]);
  }
  __syncthreads();
  int ll = t >> 3, kq = t & 7;
#pragma unroll
  for (int n = 0; n < 8; ++n) {
    ushort4 o;
    o.x = stile[n][kq * 4 + 0][ll];
    o.y = stile[n][kq * 4 + 1][ll];
    o.z = stile[n][kq * 4 + 2][ll];
    o.w = stile[n][kq * 4 + 3][ll];
    *(ushort4*)(wT + ((size_t)n << 20) + (size_t)(l0 + ll) * 1024 + k0 + kq * 4) = o;
  }
}

// ---------------- batched GEMM: out[b][n][l] = sum_k xT[n][b][k] * wT[n][l][k] ----------
// (unchanged — verified at <40 us in the 8-kernel pipeline)
__global__ __launch_bounds__(256, 2)
void k_gemm(const unsigned short* __restrict__ xT, const unsigned short* __restrict__ wT,
            float* __restrict__ out) {
  __shared__ bf16x8 sA[1024];   // 128 rows x 8 chunks = 16 KB
  __shared__ bf16x8 sB[1024];
  const int n  = blockIdx.x;
  const int m0 = blockIdx.y * 128;
  const int l0 = blockIdx.z * 128;
  const int tid = threadIdx.x;
  const int lane = tid & 63;
  const int wv = tid >> 6;
  const int wm = (wv & 1) * 64;
  const int wl = (wv >> 1) * 64;
  const unsigned short* A  = xT + ((size_t)n << 20);
  const unsigned short* Bt = wT + ((size_t)n << 20);

  v4f acc[4][4] = {};
  const int quad = lane >> 4;
  const int r16 = lane & 15;

  for (int kt = 0; kt < 1024; kt += 64) {
#pragma unroll
    for (int rr = 0; rr < 4; ++rr) {
      int cb = rr * 4 + wv;            // chunk-block 0..15
      int c = cb * 64 + lane;          // chunk 0..1023
      int row = c >> 3;
      int gc = (c & 7) ^ (row & 7);    // swizzled source column
      const unsigned short* ga = A  + (size_t)(m0 + row) * 1024 + kt + gc * 8;
      const unsigned short* gb = Bt + (size_t)(l0 + row) * 1024 + kt + gc * 8;
      __builtin_amdgcn_global_load_lds((const __attribute__((address_space(1))) void*)ga,
                                       (__attribute__((address_space(3))) void*)&sA[cb * 64],
                                       16, 0, 0);
      __builtin_amdgcn_global_load_lds((const __attribute__((address_space(1))) void*)gb,
                                       (__attribute__((address_space(3))) void*)&sB[cb * 64],
                                       16, 0, 0);
    }
    asm volatile("s_waitcnt vmcnt(0)" ::: "memory");
    __syncthreads();

#pragma unroll
    for (int ks = 0; ks < 2; ++ks) {
      bf16x8 af[4], bfr[4];
#pragma unroll
      for (int tt = 0; tt < 4; ++tt) {
        int arow = wm + tt * 16 + r16;
        af[tt] = sA[arow * 8 + ((ks * 4 + quad) ^ (arow & 7))];
        int brow = wl + tt * 16 + r16;
        bfr[tt] = sB[brow * 8 + ((ks * 4 + quad) ^ (brow & 7))];
      }
#pragma unroll
      for (int tm = 0; tm < 4; ++tm)
#pragma unroll
        for (int tn = 0; tn < 4; ++tn)
          acc[tm][tn] = __builtin_amdgcn_mfma_f32_16x16x32_bf16(af[tm], bfr[tn], acc[tm][tn], 0, 0, 0);
    }
    __syncthreads();
  }

#pragma unroll
  for (int tm = 0; tm < 4; ++tm)
#pragma unroll
    for (int tn = 0; tn < 4; ++tn)
#pragma unroll
      for (int rr = 0; rr < 4; ++rr) {
        int row = m0 + wm + tm * 16 + quad * 4 + rr;
        int col = l0 + wl + tn * 16 + r16;
        out[(size_t)(row * 8 + n) * 1024 + col] = acc[tm][tn][rr];
      }
}

extern "C" void kernel_launch(void* const* d_in, const int* in_sizes, int n_in,
                              void* d_out, int out_size, void* d_ws, size_t ws_size,
                              hipStream_t stream) {
  const float* x = (const float*)d_in[0];
  const float* U = (const float*)d_in[1];
  const float* thres = (const float*)d_in[2];
  float* out = (float*)d_out;

  char* w = (char*)d_ws;
  float2* mmpart = (float2*)w;                                   // 8 KB
  Partial* part  = (Partial*)(w + 8192);                         // 64 KB
  Partial* part2 = (Partial*)(w + 8192 + 65536);                 // 64 KB
  unsigned short* xT = (unsigned short*)(w + (1 << 20));         // 16 MB
  unsigned short* wT = xT + ((size_t)8 << 20);                   // 16 MB

  k1_minmax_xpack<<<3072, 256, 0, stream>>>((const float4*)U, mmpart, x, xT);
  k2_stats0<<<1024, 256, 0, stream>>>(U, mmpart, part);
  k3a_stats1<<<1024, 256, 0, stream>>>(U, mmpart, part, part2, thres);
  k3b_final<<<1024, 256, 0, stream>>>(U, mmpart, part, part2, thres, wT);
  k_gemm<<<dim3(8, 8, 8), 256, 0, stream>>>(xT, wT, out);
}

// Round 3
// 167.991 us; speedup vs baseline: 1.0008x; 1.0008x over previous
//
#include <hip/hip_runtime.h>
#include <hip/hip_bf16.h>
#include <stdint.h>

// Problem constants: N=8, D1=1024, D2=1024, B=1024, D = D1*D2 = 2^20
#define DD (1 << 20)

typedef float v4f __attribute__((ext_vector_type(4)));
typedef __bf16 bf16x8 __attribute__((ext_vector_type(8)));

struct Scalars {
  float s;             // step size at this stage
  int   uniform;       // 1 if all rows in one group
  float coef[8];       // gradg[gid[i]] per sorted position i
  float cnti[8];       // max(counts[gid[i]],1) per sorted position i
  int   isend[8];      // 1 if sorted position i ends its group
};

struct Partial {       // per-block gap stats (1024 blocks)
  double g[7];
  double mx;
};

static __device__ __forceinline__ unsigned short f2bf(float v) {
  unsigned u = __float_as_uint(v);
  u += 0x7fffu + ((u >> 16) & 1u);   // round-to-nearest-even
  return (unsigned short)(u >> 16);
}

// keyed 19-CE Batcher network; lexicographic (val, idx) == stable argsort
#define CE2(a, b)                                                        \
  { float ra = r[a], rb = r[b]; int oa = ord[a], ob = ord[b];            \
    bool sw = (ra > rb) || (ra == rb && oa > ob);                        \
    r[a] = sw ? rb : ra; r[b] = sw ? ra : rb;                            \
    ord[a] = sw ? ob : oa; ord[b] = sw ? oa : ob; }

#define SORTNET8                                                          \
  CE2(0,1) CE2(2,3) CE2(4,5) CE2(6,7)                                     \
  CE2(0,2) CE2(1,3) CE2(4,6) CE2(5,7)                                     \
  CE2(1,2) CE2(5,6)                                                       \
  CE2(0,4) CE2(1,5) CE2(2,6) CE2(3,7)                                     \
  CE2(2,4) CE2(3,5)                                                       \
  CE2(1,2) CE2(3,4) CE2(5,6)

// value-only network (stats / uniform path need only sorted values)
#define CEV(a, b) { float ra = q[a], rb = q[b]; q[a] = fminf(ra, rb); q[b] = fmaxf(ra, rb); }
#define SORTNET8V                                                         \
  CEV(0,1) CEV(2,3) CEV(4,5) CEV(6,7)                                     \
  CEV(0,2) CEV(1,3) CEV(4,6) CEV(5,7)                                     \
  CEV(1,2) CEV(5,6)                                                       \
  CEV(0,4) CEV(1,5) CEV(2,6) CEV(3,7)                                     \
  CEV(2,4) CEV(3,5)                                                       \
  CEV(1,2) CEV(3,4) CEV(5,6)

// block-reduce 7 gap sums + max, write to po
static __device__ __forceinline__ void stats_block_reduce(float dl[7], float mx,
                                                          Partial* __restrict__ po) {
#pragma unroll
  for (int off = 32; off; off >>= 1) {
#pragma unroll
    for (int g = 0; g < 7; ++g) dl[g] += __shfl_down(dl[g], off, 64);
    mx = fmaxf(mx, __shfl_down(mx, off, 64));
  }
  __shared__ double wsum[4][7];
  __shared__ float wmax[4];
  int lane = threadIdx.x & 63, wv = threadIdx.x >> 6;
  if (lane == 0) {
#pragma unroll
    for (int g = 0; g < 7; ++g) wsum[wv][g] = (double)dl[g];
    wmax[wv] = mx;
  }
  __syncthreads();
  if (threadIdx.x == 0) {
#pragma unroll
    for (int g = 0; g < 7; ++g)
      po->g[g] = wsum[0][g] + wsum[1][g] + wsum[2][g] + wsum[3][g];
    po->mx = (double)fmaxf(fmaxf(wmax[0], wmax[1]), fmaxf(wmax[2], wmax[3]));
  }
}

// every block redundantly reduces mmpart[1024] -> s0 (8 KB from L2, ~free)
static __device__ __forceinline__ float compute_s0(const float2* __restrict__ mmpart) {
  __shared__ float2 wmm[4];
  __shared__ float sS0;
  int t = threadIdx.x;
  float mn = 3.4e38f, mxv = -3.4e38f;
#pragma unroll
  for (int j = 0; j < 4; ++j) {
    float2 p = mmpart[j * 256 + t];
    mn = fminf(mn, p.x); mxv = fmaxf(mxv, p.y);
  }
#pragma unroll
  for (int off = 32; off; off >>= 1) {
    mn = fminf(mn, __shfl_down(mn, off, 64));
    mxv = fmaxf(mxv, __shfl_down(mxv, off, 64));
  }
  int lane = t & 63, wv = t >> 6;
  if (lane == 0) wmm[wv] = make_float2(mn, mxv);
  __syncthreads();
  if (t == 0) {
    for (int i = 1; i < 4; ++i) { mn = fminf(mn, wmm[i].x); mxv = fmaxf(mxv, wmm[i].y); }
    sS0 = (mxv - mn) / 3.0f;        // RES_DENOS[0] = 3.0
  }
  __syncthreads();
  return sS0;
}

// every block redundantly reduces part[1024] (64 KB from L2); result valid on t==0 only
static __device__ __forceinline__ void reduce_partials(const Partial* __restrict__ part,
                                                       double g[7], double& mx) {
  __shared__ double sg[4][8];
  int t = threadIdx.x;
  __syncthreads();               // protect sg reuse across calls
#pragma unroll
  for (int i = 0; i < 7; ++i) g[i] = 0.0;
  mx = 0.0;
#pragma unroll
  for (int j = 0; j < 4; ++j) {
    const Partial& p = part[j * 256 + t];
#pragma unroll
    for (int i = 0; i < 7; ++i) g[i] += p.g[i];
    mx = fmax(mx, p.mx);
  }
#pragma unroll
  for (int off = 32; off; off >>= 1) {
#pragma unroll
    for (int i = 0; i < 7; ++i) g[i] += __shfl_down(g[i], off, 64);
    mx = fmax(mx, __shfl_down(mx, off, 64));
  }
  int lane = t & 63, wv = t >> 6;
  if (lane == 0) {
#pragma unroll
    for (int i = 0; i < 7; ++i) sg[wv][i] = g[i];
    sg[wv][7] = mx;
  }
  __syncthreads();
  if (t == 0) {
#pragma unroll
    for (int i = 0; i < 7; ++i) g[i] = sg[0][i] + sg[1][i] + sg[2][i] + sg[3][i];
    mx = fmax(fmax(sg[0][7], sg[1][7]), fmax(sg[2][7], sg[3][7]));
  }
}

// exact mirror of the former k_scalars2 t==0 tail (call on t==0 only; sc in LDS)
static __device__ void make_scalars(const double g[7], double mx, float s_prev, float deno,
                                    float thres0, Scalars* sc, bool* sat) {
  float s = s_prev / deno;
  sc->s = s;
  float md = (float)mx;
  float sigT = 1.f / (1.f + expf(-thres0));
  float sp[7], bb[7];
  float zmax = -1e30f;
  for (int gg = 0; gg < 7; ++gg) {
    float mean = (float)(g[gg] / ((double)DD * (double)md));
    float z = (mean - sigT) / 0.01f;     // SPLIT_TEMP
    zmax = fmaxf(zmax, z);
    sp[gg] = 1.f / (1.f + expf(-z));
    bb[gg] = rintf(sp[gg]);              // jnp.round = RNE
  }
  int gid[8]; gid[0] = 0;
  for (int i = 1; i < 8; ++i) gid[i] = gid[i - 1] + (int)bb[i - 1];
  float counts[8] = {0, 0, 0, 0, 0, 0, 0, 0};
  for (int i = 0; i < 8; ++i) counts[gid[i]] += 1.f;
  float lsum[8] = {0, 0, 0, 0, 0, 0, 0, 0};
  for (int i = 0; i < 7; ++i) {
    float f = (bb[i] == 1.f) ? sp[i] : (1.f - sp[i]);
    lsum[gid[i]] += logf(f);
  }
  float gradg[8];
  for (int gg = 0; gg < 8; ++gg) gradg[gg] = expf(lsum[gg]);
  for (int i = 0; i < 8; ++i) {
    sc->coef[i] = gradg[gid[i]];
    sc->cnti[i] = fmaxf(counts[gid[i]], 1.f);
    sc->isend[i] = (i == 7) || (gid[i + 1] != gid[i]);
  }
  int uni = (gid[7] == 0) ? 1 : 0;
  sc->uniform = uni;
  // saturation certain -> next stage is analytic (b=0, coef=1, cnti=8), bit-exact
  *sat = (uni && zmax < -21.0f);
}

// ---------------- general per-column update core (keyed sort + scatter) ----------------
static __device__ __forceinline__ void update_core(const float u[8], const float vo[8],
                                                   const Scalars* __restrict__ sc,
                                                   float vnew[8]) {
  float s = sc->s;
  float coef[8], cnti[8]; int isend[8];
#pragma unroll
  for (int i = 0; i < 8; ++i) { coef[i] = sc->coef[i]; cnti[i] = sc->cnti[i]; isend[i] = sc->isend[i]; }
  float r[8]; int ord[8];
#pragma unroll
  for (int n = 0; n < 8; ++n) { r[n] = u[n] - vo[n]; ord[n] = n; }
  SORTNET8
  float endsum[8]; float a = 0.f;
#pragma unroll
  for (int i = 0; i < 8; ++i) { a += r[i]; endsum[i] = a; if (isend[i]) a = 0.f; }
  float t[8]; float gsv = 0.f;
#pragma unroll
  for (int i = 7; i >= 0; --i) {
    if (isend[i]) gsv = endsum[i];
    t[i] = coef[i] * (gsv / cnti[i]);
  }
#pragma unroll
  for (int n = 0; n < 8; ++n) {
    float tv = 0.f;
#pragma unroll
    for (int i = 0; i < 8; ++i) tv = (ord[i] == n) ? t[i] : tv;
    vnew[n] = vo[n] + s * floorf(tv / s);
  }
}

// uniform (single-group) core: value-sort for the bit-exact sorted-order sum
static __device__ __forceinline__ float uniform_delta(const float u[8], const float vo[8],
                                                      float coef0, float cnt0, float s) {
  float q[8];
#pragma unroll
  for (int n = 0; n < 8; ++n) q[n] = u[n] - vo[n];
  SORTNET8V
  float a = 0.f;
#pragma unroll
  for (int i = 0; i < 8; ++i) a += q[i];
  float t = coef0 * (a / cnt0);
  return s * floorf(t / s);
}

static __device__ __forceinline__ void apply_update(const float u[8], const float vo[8],
                                                    const Scalars* __restrict__ sc,
                                                    float vnew[8]) {
  if (sc->uniform) {
    float c = uniform_delta(u, vo, sc->coef[0], sc->cnti[0], sc->s);
#pragma unroll
    for (int n = 0; n < 8; ++n) vnew[n] = vo[n] + c;
  } else {
    update_core(u, vo, sc, vnew);
  }
}

// ---------------- k1: minmax partials (1024 blocks) + x -> bf16 xT pack (2048 blocks) --
__global__ __launch_bounds__(256)
void k1_minmax_xpack(const float4* __restrict__ U4, float2* __restrict__ mmpart,
                     const float* __restrict__ x, unsigned short* __restrict__ xT) {
  int tid = threadIdx.x;
  if (blockIdx.x < 1024) {
    int bid = blockIdx.x;
    float mn = 3.4e38f, mx = -3.4e38f;
#pragma unroll
    for (int j = 0; j < 8; ++j) {
      float4 v = U4[(size_t)(bid * 8 + j) * 256 + tid];
      mn = fminf(mn, fminf(fminf(v.x, v.y), fminf(v.z, v.w)));
      mx = fmaxf(mx, fmaxf(fmaxf(v.x, v.y), fmaxf(v.z, v.w)));
    }
#pragma unroll
    for (int off = 32; off; off >>= 1) {
      mn = fminf(mn, __shfl_down(mn, off, 64));
      mx = fmaxf(mx, __shfl_down(mx, off, 64));
    }
    __shared__ float2 w4[4];
    if ((tid & 63) == 0) w4[tid >> 6] = make_float2(mn, mx);
    __syncthreads();
    if (tid == 0) {
      for (int i = 1; i < 4; ++i) { mn = fminf(mn, w4[i].x); mx = fmaxf(mx, w4[i].y); }
      mmpart[bid] = make_float2(mn, mx);
    }
  } else {
    int bid2 = blockIdx.x - 1024;          // 0..2047
#pragma unroll
    for (int j = 0; j < 4; ++j) {
      int i = j * (2048 * 256) + bid2 * 256 + tid;
      int kq = i & 255;
      int b  = (i >> 8) & 1023;
      int n  = i >> 18;
      float4 v = *(const float4*)(x + ((size_t)(b * 8 + n) << 10) + (kq << 2));
      ushort4 o = make_ushort4(f2bf(v.x), f2bf(v.y), f2bf(v.z), f2bf(v.w));
      *(ushort4*)(xT + (((size_t)(n << 10 | b)) << 10) + (kq << 2)) = o;
    }
  }
}

// ---------------- k2: s0 inline + stage-1 gap stats (1024 blocks, 4 cols/thread) ------
__global__ __launch_bounds__(256)
void k2_stats0(const float* __restrict__ U, const float2* __restrict__ mmpart,
               Partial* __restrict__ part) {
  float s0 = compute_s0(mmpart);
  int t = threadIdx.x;
  size_t d0 = (size_t)blockIdx.x * 1024 + t * 4;
  float4 u4[8];
#pragma unroll
  for (int n = 0; n < 8; ++n) u4[n] = *(const float4*)(U + ((size_t)n << 20) + d0);
  float dl[7] = {0, 0, 0, 0, 0, 0, 0};
  float mxv = 0.f;
#pragma unroll
  for (int j = 0; j < 4; ++j) {
    float q[8];
#pragma unroll
    for (int n = 0; n < 8; ++n) {
      float u = ((const float*)&u4[n])[j];
      q[n] = u - s0 * floorf(u / s0);
    }
    SORTNET8V
#pragma unroll
    for (int g = 0; g < 7; ++g) { float dd = q[g + 1] - q[g]; dl[g] += dd; mxv = fmaxf(mxv, dd); }
  }
  stats_block_reduce(dl, mxv, &part[blockIdx.x]);
}

// ---------------- k3a: sc1 inline; early-out if stage-2 analytic; else stage-2 stats ---
__global__ __launch_bounds__(256)
void k3a_stats1(const float* __restrict__ U, const float2* __restrict__ mmpart,
                const Partial* __restrict__ part, Partial* __restrict__ part2,
                const float* __restrict__ thres) {
  __shared__ Scalars ssc1;
  __shared__ int ssat;
  float s0 = compute_s0(mmpart);
  double g[7]; double mx;
  reduce_partials(part, g, mx);
  if (threadIdx.x == 0) {
    bool sat;
    make_scalars(g, mx, s0, 5.0f, thres[0], &ssc1, &sat);
    ssat = sat ? 1 : 0;
  }
  __syncthreads();
  if (ssat) return;                        // stage 2 analytic: no stats pass needed

  int t = threadIdx.x;
  size_t d0 = (size_t)blockIdx.x * 1024 + t * 4;
  float4 u4[8];
#pragma unroll
  for (int n = 0; n < 8; ++n) u4[n] = *(const float4*)(U + ((size_t)n << 20) + d0);
  float dl[7] = {0, 0, 0, 0, 0, 0, 0};
  float mxv = 0.f;
#pragma unroll
  for (int j = 0; j < 4; ++j) {
    float u[8], v0[8], v1[8];
#pragma unroll
    for (int n = 0; n < 8; ++n) {
      u[n] = ((const float*)&u4[n])[j];
      v0[n] = s0 * floorf(u[n] / s0);
    }
    apply_update(u, v0, &ssc1, v1);
    float q[8];
#pragma unroll
    for (int n = 0; n < 8; ++n) q[n] = u[n] - v1[n];
    SORTNET8V
#pragma unroll
    for (int gg = 0; gg < 7; ++gg) { float dd = q[gg + 1] - q[gg]; dl[gg] += dd; mxv = fmaxf(mxv, dd); }
  }
  stats_block_reduce(dl, mxv, &part2[blockIdx.x]);
}

// ---------------- k3b: sc1+sc2 inline -> v0 -> v1 -> v2 -> bf16 -> wT[n][l][k] ---------
__global__ __launch_bounds__(256)
void k3b_final(const float* __restrict__ U, const float2* __restrict__ mmpart,
               const Partial* __restrict__ part, const Partial* __restrict__ part2,
               const float* __restrict__ thres, unsigned short* __restrict__ wT) {
  __shared__ Scalars ssc1, ssc2;
  __shared__ int ssat;
  __shared__ unsigned short stile[8][32][34];
  int t = threadIdx.x;
  float s0 = compute_s0(mmpart);
  {
    double g[7]; double mx;
    reduce_partials(part, g, mx);
    if (t == 0) {
      bool sat;
      make_scalars(g, mx, s0, 5.0f, thres[0], &ssc1, &sat);
      ssat = sat ? 1 : 0;
    }
  }
  __syncthreads();
  if (!ssat) {
    double g[7]; double mx;
    reduce_partials(part2, g, mx);
    if (t == 0) {
      bool sat2;
      make_scalars(g, mx, ssc1.s, 17.0f, thres[0], &ssc2, &sat2);
    }
  } else if (t == 0) {
    ssc2.s = ssc1.s / 17.0f;
    ssc2.uniform = 1;
#pragma unroll
    for (int i = 0; i < 8; ++i) {
      ssc2.coef[i] = 1.0f;
      ssc2.cnti[i] = 8.0f;
      ssc2.isend[i] = (i == 7) ? 1 : 0;
    }
  }
  __syncthreads();

  int k0 = (blockIdx.x >> 5) * 32;
  int l0 = (blockIdx.x & 31) * 32;
  int kk = t >> 3;            // 0..31
  int lq = t & 7;             // 4 cols each
  int d0 = (k0 + kk) * 1024 + l0 + lq * 4;
  float4 u4[8];
#pragma unroll
  for (int n = 0; n < 8; ++n) u4[n] = *(const float4*)(U + ((size_t)n << 20) + d0);
#pragma unroll
  for (int j = 0; j < 4; ++j) {
    float u[8], v0[8], v1[8], v2[8];
#pragma unroll
    for (int n = 0; n < 8; ++n) {
      u[n] = ((const float*)&u4[n])[j];
      v0[n] = s0 * floorf(u[n] / s0);
    }
    apply_update(u, v0, &ssc1, v1);
    apply_update(u, v1, &ssc2, v2);
#pragma unroll
    for (int n = 0; n < 8; ++n) stile[n][kk][lq * 4 + j] = f2bf(v2[n]);
  }
  __syncthreads();
  int ll = t >> 3, kq = t & 7;
#pragma unroll
  for (int n = 0; n < 8; ++n) {
    ushort4 o;
    o.x = stile[n][kq * 4 + 0][ll];
    o.y = stile[n][kq * 4 + 1][ll];
    o.z = stile[n][kq * 4 + 2][ll];
    o.w = stile[n][kq * 4 + 3][ll];
    *(ushort4*)(wT + ((size_t)n << 20) + (size_t)(l0 + ll) * 1024 + k0 + kq * 4) = o;
  }
}

// ---------------- batched GEMM: out[b][n][l] = sum_k xT[n][b][k] * wT[n][l][k] ----------
// 2-phase double-buffered K-loop (T3-minimum): issue next tile's global_load_lds BEFORE
// the MFMAs of the current tile, drain vmcnt(0)+barrier AFTER. LDS 64 KB -> 2 blocks/CU.
__global__ __launch_bounds__(256, 2)
void k_gemm(const unsigned short* __restrict__ xT, const unsigned short* __restrict__ wT,
            float* __restrict__ out) {
  __shared__ bf16x8 sA[2][1024];   // 2 x 16 KB
  __shared__ bf16x8 sB[2][1024];
  const int n  = blockIdx.x;
  const int m0 = blockIdx.y * 128;
  const int l0 = blockIdx.z * 128;
  const int tid = threadIdx.x;
  const int lane = tid & 63;
  const int wv = tid >> 6;
  const int wm = (wv & 1) * 64;
  const int wl = (wv >> 1) * 64;
  const unsigned short* A  = xT + ((size_t)n << 20);
  const unsigned short* Bt = wT + ((size_t)n << 20);

  v4f acc[4][4] = {};
  const int quad = lane >> 4;
  const int r16 = lane & 15;

#define STAGE(buf, kt)                                                              \
  {                                                                                 \
    _Pragma("unroll")                                                               \
    for (int rr = 0; rr < 4; ++rr) {                                                \
      int cb = rr * 4 + wv;            /* chunk-block 0..15 */                      \
      int c = cb * 64 + lane;          /* chunk 0..1023 */                          \
      int row = c >> 3;                                                             \
      int gc = (c & 7) ^ (row & 7);    /* swizzled source column */                 \
      const unsigned short* ga = A  + (size_t)(m0 + row) * 1024 + (kt) + gc * 8;    \
      const unsigned short* gb = Bt + (size_t)(l0 + row) * 1024 + (kt) + gc * 8;    \
      __builtin_amdgcn_global_load_lds((const __attribute__((address_space(1))) void*)ga, \
                                       (__attribute__((address_space(3))) void*)&sA[buf][cb * 64], \
                                       16, 0, 0);                                   \
      __builtin_amdgcn_global_load_lds((const __attribute__((address_space(1))) void*)gb, \
                                       (__attribute__((address_space(3))) void*)&sB[buf][cb * 64], \
                                       16, 0, 0);                                   \
    }                                                                               \
  }

  // prologue: stage tile 0, drain, barrier
  STAGE(0, 0)
  asm volatile("s_waitcnt vmcnt(0)" ::: "memory");
  __syncthreads();

  int cur = 0;
  for (int kt = 0; kt < 1024; kt += 64) {
    // issue next tile's loads first — they fly under the ds_reads + MFMAs below
    if (kt + 64 < 1024) STAGE(cur ^ 1, kt + 64)

#pragma unroll
    for (int ks = 0; ks < 2; ++ks) {
      bf16x8 af[4], bfr[4];
#pragma unroll
      for (int tt = 0; tt < 4; ++tt) {
        int arow = wm + tt * 16 + r16;
        af[tt] = sA[cur][arow * 8 + ((ks * 4 + quad) ^ (arow & 7))];
        int brow = wl + tt * 16 + r16;
        bfr[tt] = sB[cur][brow * 8 + ((ks * 4 + quad) ^ (brow & 7))];
      }
#pragma unroll
      for (int tm = 0; tm < 4; ++tm)
#pragma unroll
        for (int tn = 0; tn < 4; ++tn)
          acc[tm][tn] = __builtin_amdgcn_mfma_f32_16x16x32_bf16(af[tm], bfr[tn], acc[tm][tn], 0, 0, 0);
    }

    // drain this wave's prefetch loads, then barrier: next buffer complete for all waves,
    // and all waves' ds_reads of buf[cur] are done (barrier implies lgkmcnt drain) so the
    // next iteration may overwrite it.
    asm volatile("s_waitcnt vmcnt(0)" ::: "memory");
    __syncthreads();
    cur ^= 1;
  }
#undef STAGE

  // epilogue: D[m=quad*4+reg][l=lane&15] per 16x16 tile
#pragma unroll
  for (int tm = 0; tm < 4; ++tm)
#pragma unroll
    for (int tn = 0; tn < 4; ++tn)
#pragma unroll
      for (int rr = 0; rr < 4; ++rr) {
        int row = m0 + wm + tm * 16 + quad * 4 + rr;
        int col = l0 + wl + tn * 16 + r16;
        out[(size_t)(row * 8 + n) * 1024 + col] = acc[tm][tn][rr];
      }
}

extern "C" void kernel_launch(void* const* d_in, const int* in_sizes, int n_in,
                              void* d_out, int out_size, void* d_ws, size_t ws_size,
                              hipStream_t stream) {
  const float* x = (const float*)d_in[0];
  const float* U = (const float*)d_in[1];
  const float* thres = (const float*)d_in[2];
  float* out = (float*)d_out;

  char* w = (char*)d_ws;
  float2* mmpart = (float2*)w;                                   // 8 KB
  Partial* part  = (Partial*)(w + 8192);                         // 64 KB
  Partial* part2 = (Partial*)(w + 8192 + 65536);                 // 64 KB
  unsigned short* xT = (unsigned short*)(w + (1 << 20));         // 16 MB
  unsigned short* wT = xT + ((size_t)8 << 20);                   // 16 MB

  k1_minmax_xpack<<<3072, 256, 0, stream>>>((const float4*)U, mmpart, x, xT);
  k2_stats0<<<1024, 256, 0, stream>>>(U, mmpart, part);
  k3a_stats1<<<1024, 256, 0, stream>>>(U, mmpart, part, part2, thres);
  k3b_final<<<1024, 256, 0, stream>>>(U, mmpart, part, part2, thres, wT);
  k_gemm<<<dim3(8, 8, 8), 256, 0, stream>>>(xT, wT, out);
}